// Round 3
// baseline (769.442 us; speedup 1.0000x reference)
//
#include <hip/hip_runtime.h>
#include <hip/hip_cooperative_groups.h>

namespace cg = cooperative_groups;

// ---------------------------------------------------------------------------
// 2-layer GAT (PyG GATConv), fp32, MI355X.
// R3: (1) k_aggr XCD-split: each (node, channel-half) is its own wave; octets
//     of consecutive blocks map halves to disjoint XCD sets via blockIdx%8 ->
//     per-XCD L2 working set halves (51->25.6 MB), past-L2 fetch ~halves.
//     (2) CSR build is ONE cooperative kernel (zero/hist/scan/scatter).
//     (3) k_att fused into GEMM epilogue (shfl-reduce + fp32 atomicAdd).
//     (4) k_final: layer-2 head-mean + bias + relu + softmax.
// ---------------------------------------------------------------------------

__global__ __launch_bounds__(256)
void k_csr(const int* __restrict__ srcv, const int* __restrict__ dstv,
           int N, int E, int* __restrict__ cnt, int* __restrict__ rowptr,
           int* __restrict__ cursor, int* __restrict__ col,
           float* __restrict__ zbuf,  // a_s1,a_d1,a_s2,a_d2 = 16N floats
           int* __restrict__ blockTot) {
  cg::grid_group grid = cg::this_grid();
  const int G = gridDim.x;  // 256
  const int tid = blockIdx.x * 256 + threadIdx.x;
  const int nthr = G * 256;
  __shared__ int sm[256];

  // P0: zero counters and attention-score accumulators
  for (int i = tid; i < N; i += nthr) cnt[i] = 0;
  for (int i = tid; i < 16 * N; i += nthr) zbuf[i] = 0.f;
  grid.sync();
  // P1: histogram of dst
  for (int i = tid; i < E; i += nthr) atomicAdd(&cnt[dstv[i]], 1);
  grid.sync();
  // P2: per-block segmented exclusive scan
  const int L = (N + G - 1) / G;
  const int s0 = blockIdx.x * L;
  const int s1 = min(s0 + L, N);
  int carry = 0;
  for (int base = s0; base < s1; base += 256) {
    int i = base + threadIdx.x;
    int v = (i < s1) ? cnt[i] : 0;
    sm[threadIdx.x] = v;
    __syncthreads();
    for (int off = 1; off < 256; off <<= 1) {
      int t = (threadIdx.x >= off) ? sm[threadIdx.x - off] : 0;
      __syncthreads();
      sm[threadIdx.x] += t;
      __syncthreads();
    }
    if (i < s1) rowptr[i] = carry + sm[threadIdx.x] - v;
    carry += sm[255];
    __syncthreads();
  }
  if (threadIdx.x == 0) blockTot[blockIdx.x] = carry;
  grid.sync();
  // P3: scan the 256 block totals (block 0)
  if (blockIdx.x == 0) {
    int v = blockTot[threadIdx.x];
    sm[threadIdx.x] = v;
    __syncthreads();
    for (int off = 1; off < 256; off <<= 1) {
      int t = (threadIdx.x >= off) ? sm[threadIdx.x - off] : 0;
      __syncthreads();
      sm[threadIdx.x] += t;
      __syncthreads();
    }
    blockTot[threadIdx.x] = sm[threadIdx.x] - v;
  }
  grid.sync();
  // P4: add block offsets, init cursor
  {
    int off = blockTot[blockIdx.x];
    for (int i = s0 + threadIdx.x; i < s1; i += 256) {
      int rp = rowptr[i] + off;
      rowptr[i] = rp;
      cursor[i] = rp;
    }
  }
  if (tid == 0) rowptr[N] = E;
  grid.sync();
  // P5: scatter src into CSR col
  for (int i = tid; i < E; i += nthr) {
    int p = atomicAdd(&cursor[dstv[i]], 1);
    col[p] = srcv[i];
  }
}

// ---------------------------------------------------------------------------
// fp32 GEMM: C[N,256] = A[N,K] @ W[K,256]. 128x128 tile, 16x16 threads, 8x8
// microtile. A transposed in LDS; B panel in registers from L2.
// Epilogue: fused attention scores a_s[n,h]=sum_c h[n,c]*att_s[c] (+a_d) via
// 8-lane shfl reduce + device atomicAdd (a_s/a_d zeroed by k_csr).
// ---------------------------------------------------------------------------
__global__ __launch_bounds__(256)
void k_gemm(const float* __restrict__ A, const float* __restrict__ W,
            float* __restrict__ C, int Nrows, int K,
            const float* __restrict__ att_s, const float* __restrict__ att_d,
            float* __restrict__ a_s, float* __restrict__ a_d) {
  __shared__ float At[8][132];
  const int tx = threadIdx.x & 15;
  const int ty = threadIdx.x >> 4;
  const int row0 = blockIdx.x * 128;
  const int col0 = blockIdx.y * 128;
  const int arow = threadIdx.x >> 1;
  const int akk  = (threadIdx.x & 1) * 4;

  float acc[8][8] = {};

  for (int k0 = 0; k0 < K; k0 += 8) {
    float breg[8][8];
#pragma unroll
    for (int kk = 0; kk < 8; kk++) {
      const float* wp = W + (size_t)(k0 + kk) * 256 + col0 + tx * 8;
      float4 b0 = *(const float4*)(wp);
      float4 b1 = *(const float4*)(wp + 4);
      breg[kk][0] = b0.x; breg[kk][1] = b0.y; breg[kk][2] = b0.z; breg[kk][3] = b0.w;
      breg[kk][4] = b1.x; breg[kk][5] = b1.y; breg[kk][6] = b1.z; breg[kk][7] = b1.w;
    }
    int gr = row0 + arow;
    float4 av = make_float4(0.f, 0.f, 0.f, 0.f);
    if (gr < Nrows) av = *(const float4*)(A + (size_t)gr * K + k0 + akk);
    At[akk + 0][arow] = av.x;
    At[akk + 1][arow] = av.y;
    At[akk + 2][arow] = av.z;
    At[akk + 3][arow] = av.w;
    __syncthreads();
#pragma unroll
    for (int kk = 0; kk < 8; kk++) {
      float4 a0 = *(const float4*)(&At[kk][ty * 8]);
      float4 a1 = *(const float4*)(&At[kk][ty * 8 + 4]);
      float ar[8] = {a0.x, a0.y, a0.z, a0.w, a1.x, a1.y, a1.z, a1.w};
#pragma unroll
      for (int i = 0; i < 8; i++)
#pragma unroll
        for (int j = 0; j < 8; j++)
          acc[i][j] += ar[i] * breg[kk][j];
    }
    __syncthreads();
  }

#pragma unroll
  for (int i = 0; i < 8; i++) {
    int gr = row0 + ty * 8 + i;
    if (gr < Nrows) {
      float* cp = C + (size_t)gr * 256 + col0 + tx * 8;
      *(float4*)(cp)     = make_float4(acc[i][0], acc[i][1], acc[i][2], acc[i][3]);
      *(float4*)(cp + 4) = make_float4(acc[i][4], acc[i][5], acc[i][6], acc[i][7]);
    }
  }

  // ---- fused attention-score epilogue
  const int cbase = col0 + tx * 8;
  float asv[8], adv[8];
#pragma unroll
  for (int j = 0; j < 8; j++) { asv[j] = att_s[cbase + j]; adv[j] = att_d[cbase + j]; }
  const int head = cbase >> 6;  // tx*8 never straddles a 64 boundary
#pragma unroll
  for (int i = 0; i < 8; i++) {
    float ps = 0.f, pd = 0.f;
#pragma unroll
    for (int j = 0; j < 8; j++) { ps += acc[i][j] * asv[j]; pd += acc[i][j] * adv[j]; }
    // 8 lanes (tx&7) share one (row, head): butterfly then one atomic
    ps += __shfl_xor(ps, 1); pd += __shfl_xor(pd, 1);
    ps += __shfl_xor(ps, 2); pd += __shfl_xor(pd, 2);
    ps += __shfl_xor(ps, 4); pd += __shfl_xor(pd, 4);
    if ((tx & 7) == 0) {
      int gr = row0 + ty * 8 + i;
      if (gr < Nrows) {
        atomicAdd(&a_s[(size_t)gr * 4 + head], ps);
        atomicAdd(&a_d[(size_t)gr * 4 + head], pd);
      }
    }
  }
}

// ---------------------------------------------------------------------------
// Segment-softmax aggregation, XCD-split: one wave per (node, channel-half).
// Octet mapping: blockIdx%8 in 0..3 -> half 0 (heads 0,1), 4..7 -> half 1
// (heads 2,3); with round-robin block->XCD placement each XCD touches only
// 25.6 MB of h. Lane l owns channels half*128 + 2l (float2); hd = l>>5.
// LAYER 1: relu(acc/denom + bias) -> [N,256].
// LAYER 2: write normalized per-head values -> temp [N,256] (k_final mixes).
// ---------------------------------------------------------------------------
template <int LAYER>
__global__ __launch_bounds__(256)
void k_aggr(const float* __restrict__ hsrc, const int* __restrict__ rowptr,
            const int* __restrict__ col, const float* __restrict__ a_s,
            const float* __restrict__ a_d, const float* __restrict__ bias,
            float* __restrict__ outp, int N) {
  __shared__ int   s_sh[4][64];
  __shared__ float w_sh[4][128];
  const int wv = threadIdx.x >> 6;
  const int lane = threadIdx.x & 63;
  const int g = blockIdx.x >> 3;
  const int s8 = blockIdx.x & 7;
  const int half = s8 >> 2;
  const int node = g * 16 + (s8 & 3) * 4 + wv;
  if (node >= N) return;
  const int hd = lane >> 5;
  const int beg = rowptr[node], end = rowptr[node + 1];
  const float2 adst = *(const float2*)(a_d + (size_t)node * 4 + half * 2);

  float m0 = -3e38f, m1 = -3e38f;
  float d0 = 0.f, d1 = 0.f;
  float2 acc = make_float2(0.f, 0.f);

  for (int c0 = beg; c0 < end; c0 += 64) {
    int nc = min(64, end - c0);
    int s = 0;
    float e0 = -3e38f, e1 = -3e38f;
    if (lane < nc) {
      s = col[c0 + lane];
      float2 asr = *(const float2*)(a_s + (size_t)s * 4 + half * 2);
      e0 = asr.x + adst.x; e0 = e0 > 0.f ? e0 : 0.2f * e0;
      e1 = asr.y + adst.y; e1 = e1 > 0.f ? e1 : 0.2f * e1;
    }
    float c0m = e0, c1m = e1;
    for (int off = 32; off; off >>= 1) {
      c0m = fmaxf(c0m, __shfl_xor(c0m, off));
      c1m = fmaxf(c1m, __shfl_xor(c1m, off));
    }
    float nm0 = fmaxf(m0, c0m), nm1 = fmaxf(m1, c1m);
    float sc0 = __expf(m0 - nm0), sc1 = __expf(m1 - nm1);
    float p0 = 0.f, p1 = 0.f;
    if (lane < nc) { p0 = __expf(e0 - nm0); p1 = __expf(e1 - nm1); }
    float t0 = p0, t1 = p1;
    for (int off = 32; off; off >>= 1) {
      t0 += __shfl_xor(t0, off);
      t1 += __shfl_xor(t1, off);
    }
    d0 = d0 * sc0 + t0; d1 = d1 * sc1 + t1;
    float asc = (hd == 0) ? sc0 : sc1;
    acc.x *= asc; acc.y *= asc;
    m0 = nm0; m1 = nm1;

    s_sh[wv][lane] = s;
    *(float2*)(&w_sh[wv][lane * 2]) = make_float2(p0, p1);
    asm volatile("s_waitcnt lgkmcnt(0)" ::: "memory");

    const float* wrow = &w_sh[wv][hd];
    const int*   srow = &s_sh[wv][0];
    const float* hbase = hsrc + half * 128 + lane * 2;
    int j = 0;
    for (; j + 4 <= nc; j += 4) {
      int sj0 = srow[j], sj1 = srow[j + 1], sj2 = srow[j + 2], sj3 = srow[j + 3];
      float w0 = wrow[2 * j], w1 = wrow[2 * j + 2];
      float w2 = wrow[2 * j + 4], w3 = wrow[2 * j + 6];
      float2 h0 = *(const float2*)(hbase + (size_t)sj0 * 256);
      float2 h1 = *(const float2*)(hbase + (size_t)sj1 * 256);
      float2 h2 = *(const float2*)(hbase + (size_t)sj2 * 256);
      float2 h3 = *(const float2*)(hbase + (size_t)sj3 * 256);
      acc.x += w0 * h0.x; acc.y += w0 * h0.y;
      acc.x += w1 * h1.x; acc.y += w1 * h1.y;
      acc.x += w2 * h2.x; acc.y += w2 * h2.y;
      acc.x += w3 * h3.x; acc.y += w3 * h3.y;
    }
    for (; j < nc; j++) {
      int sj = srow[j];
      float w = wrow[2 * j];
      float2 hv = *(const float2*)(hbase + (size_t)sj * 256);
      acc.x += w * hv.x; acc.y += w * hv.y;
    }
  }

  float dh = (hd == 0) ? d0 : d1;
  float inv = 1.0f / dh;  // deg>=1 via self-loop
  float2 v = make_float2(acc.x * inv, acc.y * inv);
  const size_t o = (size_t)node * 256 + half * 128 + lane * 2;
  if (LAYER == 1) {
    float2 bv = *(const float2*)(bias + half * 128 + lane * 2);
    v.x = fmaxf(v.x + bv.x, 0.f);
    v.y = fmaxf(v.y + bv.y, 0.f);
    *(float2*)(outp + o) = v;
  } else {
    *(float2*)(outp + o) = v;  // normalized per-head values; k_final mixes
  }
}

// ---------------------------------------------------------------------------
// Layer-2 epilogue: head-mean + bias + relu + softmax(64). One wave per node.
// ---------------------------------------------------------------------------
__global__ __launch_bounds__(256)
void k_final(const float* __restrict__ t, const float* __restrict__ b2,
             float* __restrict__ out, int N) {
  int node = (int)((blockIdx.x * 256u + threadIdx.x) >> 6);
  int lane = threadIdx.x & 63;
  if (node >= N) return;
  const float* tr = t + (size_t)node * 256;
  float v = 0.25f * (tr[lane] + tr[64 + lane] + tr[128 + lane] + tr[192 + lane]) + b2[lane];
  v = fmaxf(v, 0.f);
  float mx = v;
  for (int off = 32; off; off >>= 1) mx = fmaxf(mx, __shfl_xor(mx, off));
  float e = __expf(v - mx);
  float sum = e;
  for (int off = 32; off; off >>= 1) sum += __shfl_xor(sum, off);
  out[(size_t)node * 64 + lane] = e / sum;
}

// ---------------------------------------------------------------------------

extern "C" void kernel_launch(void* const* d_in, const int* in_sizes, int n_in,
                              void* d_out, int out_size, void* d_ws, size_t ws_size,
                              hipStream_t stream) {
  const float* x   = (const float*)d_in[0];
  const int*   ei  = (const int*)d_in[1];
  const float* W1  = (const float*)d_in[2];
  const float* as1 = (const float*)d_in[3];
  const float* ad1 = (const float*)d_in[4];
  const float* b1  = (const float*)d_in[5];
  const float* W2  = (const float*)d_in[6];
  const float* as2 = (const float*)d_in[7];
  const float* ad2 = (const float*)d_in[8];
  const float* b2  = (const float*)d_in[9];
  float* out = (float*)d_out;

  int N = in_sizes[0] / 128;
  int E = in_sizes[1] / 2;
  int* srcv_p = (int*)ei;
  int* dstv_p = (int*)(ei + E);

  float* h      = (float*)d_ws;                 // [N,256]
  float* hb     = h + (size_t)N * 256;          // [N,256] (layer2 temp too)
  float* zbuf   = hb + (size_t)N * 256;         // a_s1,a_d1,a_s2,a_d2 [16N]
  float* a_s1 = zbuf;
  float* a_d1 = a_s1 + (size_t)N * 4;
  float* a_s2 = a_d1 + (size_t)N * 4;
  float* a_d2 = a_s2 + (size_t)N * 4;
  int*   rowptr = (int*)(zbuf + (size_t)N * 16);  // [N+1] (+pad)
  int*   cnt    = rowptr + (N + 4);               // [N]
  int*   cursor = cnt + N;                        // [N]
  int*   col    = cursor + N;                     // [E]
  int*   blockTot = col + E;                      // [256]

  // --- CSR build + zeroing: one cooperative kernel
  {
    void* args[] = {&srcv_p, &dstv_p, &N, &E, &cnt, &rowptr, &cursor, &col,
                    &zbuf, &blockTot};
    hipLaunchCooperativeKernel((const void*)k_csr, dim3(256), dim3(256),
                               args, 0, stream);
  }

  dim3 gg((N + 127) / 128, 2);
  const int ab = ((N + 15) / 16) * 8;  // aggr: octet-mapped (node, half) waves
  const int wb = (N + 3) / 4;          // wave-per-node kernels

  k_gemm<<<gg, 256, 0, stream>>>(x, W1, h, N, 128, as1, ad1, a_s1, a_d1);
  k_aggr<1><<<ab, 256, 0, stream>>>(h, rowptr, col, a_s1, a_d1, b1, hb, N);
  k_gemm<<<gg, 256, 0, stream>>>(hb, W2, h, N, 256, as2, ad2, a_s2, a_d2);
  k_aggr<2><<<ab, 256, 0, stream>>>(h, rowptr, col, a_s2, a_d2, b2, hb, N);
  k_final<<<wb, 256, 0, stream>>>(hb, b2, out, N);
}